// Round 5
// baseline (339.349 us; speedup 1.0000x reference)
//
#include <hip/hip_runtime.h>
#include <math.h>

// EdgeEmbedding — R4 wave-independent kernel, x3 REPLAY DIAGNOSTIC.
//
// Purpose of this round: measure the kernel's true standalone duration and
// its own rocprof counters. The harness's ~131 us poison fill hides every
// dispatch below its duration; three structurally disjoint kernels produced
// identical totals, so we must separate kernel time from in-region harness
// overhead. The body below executes reps=3 times (idempotent rewrites of
// identical values; nt stores are side-effecting so nothing is DCE'd):
//   kernel_true = (total_this_round - 257.2) / 2
// and at ~3x duration the kernel dispatch should clear the 131 us top-k
// cutoff and expose FETCH/WRITE/VALUBusy for the kernel itself.
//
// Kernel structure is identical to R4 (barrier-free, per-wave LDS slices,
// rcp instead of divides, 32-bit f4 indices, nt stores).

#define TPB 256

typedef float f32x4 __attribute__((ext_vector_type(4)));

__global__ __launch_bounds__(TPB) void edge_kernel(const float* __restrict__ edge_vec,
                                                   const unsigned char* __restrict__ rev,
                                                   const float* __restrict__ coeffs,
                                                   float* __restrict__ out, int E,
                                                   int reps) {
    __shared__ float s_vec[4][192];     // per-wave: 48 f4 of edge_vec
    __shared__ float s_emb[4][576];     // per-wave: stride 9 (8 used + pad)
    __shared__ float s_attr[4][576];    // per-wave: 64 edges x 9, contiguous

    const int t    = threadIdx.x;
    const int wid  = t >> 6;
    const int lane = t & 63;
    const int e    = blockIdx.x * TPB + t;        // < 2^31
    const bool valid = e < E;
    const int we0  = blockIdx.x * TPB + (wid << 6);   // wave's first edge

    // --- bool storage-width detect (first 4096 B of rev, L2-hot).
    bool wide;
    {
        const uint4* rw = (const uint4*)rev;
        unsigned bad = 0;
#pragma unroll
        for (int k = 0; k < 4; k++) {
            uint4 w = rw[lane + 64 * k];
            bad |= (w.x > 1u) | (w.y > 1u) | (w.z > 1u) | (w.w > 1u);
        }
        wide = !__any(bad);
    }

    for (int rep = 0; rep < reps; ++rep) {
        // --- stage this wave's edge_vec chunk: 48 contiguous float4
        {
            const float4* gvec = (const float4*)edge_vec;
            if (lane < 48) {
                int g4 = ((we0 * 3) >> 2) + lane;     // we0*3 divisible by 4
                if (4 * g4 < 3 * E) ((float4*)s_vec[wid])[lane] = gvec[g4];
            }
        }
        bool isrev = valid &&
            ((wide ? ((const unsigned*)rev)[e] : (unsigned)rev[e]) != 0);

        // same-wave ds_write -> ds_read ordered by lgkmcnt; no barrier
        float o  = isrev ? -1.0f : 1.0f;
        float px = s_vec[wid][3 * lane + 0] * o;
        float py = s_vec[wid][3 * lane + 1] * o;
        float pz = s_vec[wid][3 * lane + 2] * o;

        float r    = sqrtf(px * px + py * py + pz * pz);
        float rs   = fmaxf(r, 1e-12f);
        float rinv = __builtin_amdgcn_rcpf(rs);       // v_rcp_f32, ~1 ulp

        if (valid) __builtin_nontemporal_store(r, &out[e]);

        // poly_cutoff p=6: 1 - 28 x^6 + 48 x^7 - 21 x^8, zero at x>=1
        float xr = r * 0.2f;                           // r / RC, RC=5
        float x3 = xr * xr * xr;
        float x6 = x3 * x3;
        float env = 1.0f - 28.0f * x6 + 48.0f * x6 * xr - 21.0f * x6 * xr * xr;
        env = (xr < 1.0f) ? env : 0.0f;

        float pref = 0.632455532034f * rinv * env;     // sqrt(2/5)
#pragma unroll
        for (int j = 0; j < 8; j++)
            s_emb[wid][9 * lane + j] = pref * __sinf(coeffs[j] * xr);

        float ux = px * rinv, uy = py * rinv, uz = pz * rinv;
        const float s3 = 1.73205080757f, s15 = 3.87298334621f, s5 = 2.2360679775f;
        float sh1 = s3 * ux, sh2 = s3 * uy, sh3 = s3 * uz;
        if (isrev) { sh1 = -sh1; sh2 = -sh2; sh3 = -sh3; }   // SH parity l=1
        s_attr[wid][9 * lane + 0] = 1.0f;
        s_attr[wid][9 * lane + 1] = sh1;
        s_attr[wid][9 * lane + 2] = sh2;
        s_attr[wid][9 * lane + 3] = sh3;
        s_attr[wid][9 * lane + 4] = s15 * ux * uy;
        s_attr[wid][9 * lane + 5] = s15 * uy * uz;
        s_attr[wid][9 * lane + 6] = 0.5f * s5 * (3.0f * uz * uz - 1.0f);
        s_attr[wid][9 * lane + 7] = s15 * ux * uz;
        s_attr[wid][9 * lane + 8] = 0.5f * s15 * (ux * ux - uy * uy);

        // --- per-wave coalesced nt stores
        f32x4* o4 = (f32x4*)out;

        // edge_embedding region: floats [E, 9E); wave chunk = 128 f4
        {
            int embB4   = (E >> 2) + (we0 << 1);
            int embEnd4 = (9 * E) >> 2;
#pragma unroll
            for (int kk = 0; kk < 2; kk++) {
                int k  = lane + (kk << 6);
                int g4 = embB4 + k;
                if (g4 < embEnd4) {
                    int f0 = k << 2;   // stride-8 layout within chunk
                    f32x4 v;
                    v.x = s_emb[wid][9 * ((f0 + 0) >> 3) + ((f0 + 0) & 7)];
                    v.y = s_emb[wid][9 * ((f0 + 1) >> 3) + ((f0 + 1) & 7)];
                    v.z = s_emb[wid][9 * ((f0 + 2) >> 3) + ((f0 + 2) & 7)];
                    v.w = s_emb[wid][9 * ((f0 + 3) >> 3) + ((f0 + 3) & 7)];
                    __builtin_nontemporal_store(v, &o4[g4]);
                }
            }
        }

        // edge_attr region: floats [9E, 18E); wave chunk = 144 f4
        {
            int attrB4   = ((9 * E) >> 2) + ((9 * we0) >> 2);   // div by 4
            int attrEnd4 = (18 * E) >> 2;                       // < 2^31
#pragma unroll
            for (int kk = 0; kk < 3; kk++) {
                int k = lane + (kk << 6);
                if (k < 144) {
                    int g4 = attrB4 + k;
                    if (g4 < attrEnd4) {
                        f32x4 v = ((f32x4*)s_attr[wid])[k];
                        __builtin_nontemporal_store(v, &o4[g4]);
                    }
                }
            }
        }
    }
}

extern "C" void kernel_launch(void* const* d_in, const int* in_sizes, int n_in,
                              void* d_out, int out_size, void* d_ws, size_t ws_size,
                              hipStream_t stream) {
    const float* edge_vec = (const float*)d_in[0];
    const float* coeffs   = (const float*)d_in[1];
    const unsigned char* rev = (const unsigned char*)d_in[3];

    int E = in_sizes[2];          // 2P edges
    float* out = (float*)d_out;

    int eblocks = (E + TPB - 1) / TPB;
    // reps=3 diagnostic replay — see header comment.
    edge_kernel<<<eblocks, TPB, 0, stream>>>(edge_vec, rev, coeffs, out, E, 3);
}

// Round 6
// 260.875 us; speedup vs baseline: 1.3008x; 1.3008x over previous
//
#include <hip/hip_runtime.h>
#include <math.h>

// EdgeEmbedding — wave-independent, barrier-free, L2-combined stores.
//
// Structural identity: edge_vec[e] = pair_vec[p] * orient[e], orient = +-1,
// 2 edges per pair => each edge reconstructs pair quantities locally
// (no atomics / gather).
//
// R5 diagnostic (x3 replay) decomposed the bench: ~131 us harness poison
// fill (fixed) + ~60 us kernel + ~65 us other harness dispatches. Kernel
// floor = 252 MB @ 6.5 TB/s ~= 41 us. Marginal write BW with nt stores
// measured 5.0 TB/s vs the harness fill's 6.55 TB/s with REGULAR stores
// (same run) -> nt (L2-bypass) caps the streaming-write path.
//
// R6 changes vs R4:
//  * All output stores are REGULAR (write-combine through L2). Output is
//    write-once so L2 pollution costs nothing single-pass.
//  * s_emb is output-order contiguous with XOR-swizzled f4 slots
//    (phys = k ^ ((k>>3)&7)): emb traffic becomes 2x ds_write_b128 +
//    2x ds_read_b128 per thread (was 8 scalar writes + 4 conflicted
//    scalar reads). Swizzle spreads the stride-32B write pattern across
//    all 8 bank groups; read side is contiguous = conflict-free.
//
// Everything else per R4: zero __syncthreads (per-wave LDS slices,
// same-wave ds ordering via lgkmcnt), v_rcp_f32 instead of divides,
// 32-bit f4 output indices.

#define TPB 256

typedef float f32x4 __attribute__((ext_vector_type(4)));

__global__ __launch_bounds__(TPB) void edge_kernel(const float* __restrict__ edge_vec,
                                                   const unsigned char* __restrict__ rev,
                                                   const float* __restrict__ coeffs,
                                                   float* __restrict__ out, int E) {
    __shared__ float s_vec[4][192];     // per-wave: 48 f4 of edge_vec
    __shared__ float s_emb[4][512];     // per-wave: 128 f4, swizzled slots
    __shared__ float s_attr[4][576];    // per-wave: 64 edges x 9, contiguous

    const int t    = threadIdx.x;
    const int wid  = t >> 6;
    const int lane = t & 63;
    const int e    = blockIdx.x * TPB + t;            // < 2^31
    const bool valid = e < E;
    const int we0  = blockIdx.x * TPB + (wid << 6);   // wave's first edge

    // --- bool storage-width detect (first 4096 B of rev, L2-hot).
    // Any word > 1 => byte-packed numpy bools; else int32 storage.
    bool wide;
    {
        const uint4* rw = (const uint4*)rev;
        unsigned bad = 0;
#pragma unroll
        for (int k = 0; k < 4; k++) {
            uint4 w = rw[lane + 64 * k];
            bad |= (w.x > 1u) | (w.y > 1u) | (w.z > 1u) | (w.w > 1u);
        }
        wide = !__any(bad);
    }

    // --- stage this wave's edge_vec chunk: 48 contiguous float4
    {
        const float4* gvec = (const float4*)edge_vec;
        if (lane < 48) {
            int g4 = ((we0 * 3) >> 2) + lane;     // we0*3 divisible by 4
            if (4 * g4 < 3 * E) ((float4*)s_vec[wid])[lane] = gvec[g4];
        }
    }
    bool isrev = valid &&
        ((wide ? ((const unsigned*)rev)[e] : (unsigned)rev[e]) != 0);

    // same-wave ds_write -> ds_read ordered by lgkmcnt; no barrier needed
    float o  = isrev ? -1.0f : 1.0f;
    float px = s_vec[wid][3 * lane + 0] * o;
    float py = s_vec[wid][3 * lane + 1] * o;
    float pz = s_vec[wid][3 * lane + 2] * o;

    float r    = sqrtf(px * px + py * py + pz * pz);
    float rs   = fmaxf(r, 1e-12f);
    float rinv = __builtin_amdgcn_rcpf(rs);       // v_rcp_f32, ~1 ulp

    // edge_length: contiguous dword store
    if (valid) out[e] = r;

    // poly_cutoff p=6: 1 - 28 x^6 + 48 x^7 - 21 x^8, zero at x>=1
    float xr = r * 0.2f;                           // r / RC, RC=5
    float x3 = xr * xr * xr;
    float x6 = x3 * x3;
    float env = 1.0f - 28.0f * x6 + 48.0f * x6 * xr - 21.0f * x6 * xr * xr;
    env = (xr < 1.0f) ? env : 0.0f;

    float pref = 0.632455532034f * rinv * env;     // sqrt(2/5)

    // emb: 8 floats in output order, two swizzled b128 writes
    {
        f32x4 lo, hi;
        lo.x = pref * __sinf(coeffs[0] * xr);
        lo.y = pref * __sinf(coeffs[1] * xr);
        lo.z = pref * __sinf(coeffs[2] * xr);
        lo.w = pref * __sinf(coeffs[3] * xr);
        hi.x = pref * __sinf(coeffs[4] * xr);
        hi.y = pref * __sinf(coeffs[5] * xr);
        hi.z = pref * __sinf(coeffs[6] * xr);
        hi.w = pref * __sinf(coeffs[7] * xr);
        int s0 = 2 * lane;
        int s1 = 2 * lane + 1;
        ((f32x4*)s_emb[wid])[s0 ^ ((s0 >> 3) & 7)] = lo;
        ((f32x4*)s_emb[wid])[s1 ^ ((s1 >> 3) & 7)] = hi;
    }

    float ux = px * rinv, uy = py * rinv, uz = pz * rinv;
    const float s3 = 1.73205080757f, s15 = 3.87298334621f, s5 = 2.2360679775f;
    float sh1 = s3 * ux, sh2 = s3 * uy, sh3 = s3 * uz;
    if (isrev) { sh1 = -sh1; sh2 = -sh2; sh3 = -sh3; }   // SH parity on l=1
    s_attr[wid][9 * lane + 0] = 1.0f;
    s_attr[wid][9 * lane + 1] = sh1;
    s_attr[wid][9 * lane + 2] = sh2;
    s_attr[wid][9 * lane + 3] = sh3;
    s_attr[wid][9 * lane + 4] = s15 * ux * uy;
    s_attr[wid][9 * lane + 5] = s15 * uy * uz;
    s_attr[wid][9 * lane + 6] = 0.5f * s5 * (3.0f * uz * uz - 1.0f);
    s_attr[wid][9 * lane + 7] = s15 * ux * uz;
    s_attr[wid][9 * lane + 8] = 0.5f * s15 * (ux * ux - uy * uy);

    // --- per-wave coalesced stores (regular, L2 write-combined)
    f32x4* o4 = (f32x4*)out;

    // edge_embedding region: floats [E, 9E); wave chunk = 128 f4
    {
        int embB4   = (E >> 2) + (we0 << 1);
        int embEnd4 = (9 * E) >> 2;
#pragma unroll
        for (int kk = 0; kk < 2; kk++) {
            int k  = lane + (kk << 6);
            int g4 = embB4 + k;
            if (g4 < embEnd4)
                o4[g4] = ((f32x4*)s_emb[wid])[k ^ ((k >> 3) & 7)];
        }
    }

    // edge_attr region: floats [9E, 18E); wave chunk = 144 f4
    {
        int attrB4   = ((9 * E) >> 2) + ((9 * we0) >> 2);   // 9*we0 div by 4
        int attrEnd4 = (18 * E) >> 2;                       // 13.5M < 2^31
#pragma unroll
        for (int kk = 0; kk < 3; kk++) {
            int k = lane + (kk << 6);
            if (k < 144) {
                int g4 = attrB4 + k;
                if (g4 < attrEnd4)
                    o4[g4] = ((f32x4*)s_attr[wid])[k];
            }
        }
    }
}

extern "C" void kernel_launch(void* const* d_in, const int* in_sizes, int n_in,
                              void* d_out, int out_size, void* d_ws, size_t ws_size,
                              hipStream_t stream) {
    const float* edge_vec = (const float*)d_in[0];
    const float* coeffs   = (const float*)d_in[1];
    const unsigned char* rev = (const unsigned char*)d_in[3];

    int E = in_sizes[2];          // 2P edges
    float* out = (float*)d_out;

    int eblocks = (E + TPB - 1) / TPB;
    edge_kernel<<<eblocks, TPB, 0, stream>>>(edge_vec, rev, coeffs, out, E);
}

// Round 7
// 257.347 us; speedup vs baseline: 1.3186x; 1.0137x over previous
//
#include <hip/hip_runtime.h>
#include <math.h>

// EdgeEmbedding — final configuration: wave-independent, barrier-free,
// non-temporal stores, swizzled-b128 emb LDS.
//
// Structural identity: edge_vec[e] = pair_vec[p] * orient[e], orient = +-1,
// 2 edges per pair => each edge reconstructs pair quantities locally
// (no atomics / gather).
//
// Session ledger (total bench us; ~196 us is fixed harness fill+reset):
//   R2 short blocks + barriers + nt        255.8   <- best
//   R3 persistent pipelined + nt           266.1   (refuted: launch count)
//   R4 wave-independent + nt               257.2
//   R6 wave-independent + regular + swz    260.9   (refuted: nt-cap theory)
// R5 x3-replay decomposition: kernel ~60 us single-pass vs 41 us floor
// (216 MB writes + 48 MB reads @ 6.5 TB/s); steady-state rep = 41.1 us.
// The +19 us is compulsory: cold reads, page first-touch, launch ramp.
//
// This round: nt stores restored (top-2 measurements were nt), swizzled
// emb LDS kept (2x ds_write_b128 + 2x ds_read_b128, conflict-free; the
// old scalar layout measured 2.25M conflict-cycles in R5).

#define TPB 256

typedef float f32x4 __attribute__((ext_vector_type(4)));

__global__ __launch_bounds__(TPB) void edge_kernel(const float* __restrict__ edge_vec,
                                                   const unsigned char* __restrict__ rev,
                                                   const float* __restrict__ coeffs,
                                                   float* __restrict__ out, int E) {
    __shared__ float s_vec[4][192];     // per-wave: 48 f4 of edge_vec
    __shared__ float s_emb[4][512];     // per-wave: 128 f4, swizzled slots
    __shared__ float s_attr[4][576];    // per-wave: 64 edges x 9, contiguous

    const int t    = threadIdx.x;
    const int wid  = t >> 6;
    const int lane = t & 63;
    const int e    = blockIdx.x * TPB + t;            // < 2^31
    const bool valid = e < E;
    const int we0  = blockIdx.x * TPB + (wid << 6);   // wave's first edge

    // --- bool storage-width detect (first 4096 B of rev, L2-hot).
    // Any word > 1 => byte-packed numpy bools; else int32 storage.
    bool wide;
    {
        const uint4* rw = (const uint4*)rev;
        unsigned bad = 0;
#pragma unroll
        for (int k = 0; k < 4; k++) {
            uint4 w = rw[lane + 64 * k];
            bad |= (w.x > 1u) | (w.y > 1u) | (w.z > 1u) | (w.w > 1u);
        }
        wide = !__any(bad);
    }

    // --- stage this wave's edge_vec chunk: 48 contiguous float4
    {
        const float4* gvec = (const float4*)edge_vec;
        if (lane < 48) {
            int g4 = ((we0 * 3) >> 2) + lane;     // we0*3 divisible by 4
            if (4 * g4 < 3 * E) ((float4*)s_vec[wid])[lane] = gvec[g4];
        }
    }
    bool isrev = valid &&
        ((wide ? ((const unsigned*)rev)[e] : (unsigned)rev[e]) != 0);

    // same-wave ds_write -> ds_read ordered by lgkmcnt; no barrier needed
    float o  = isrev ? -1.0f : 1.0f;
    float px = s_vec[wid][3 * lane + 0] * o;
    float py = s_vec[wid][3 * lane + 1] * o;
    float pz = s_vec[wid][3 * lane + 2] * o;

    float r    = sqrtf(px * px + py * py + pz * pz);
    float rs   = fmaxf(r, 1e-12f);
    float rinv = __builtin_amdgcn_rcpf(rs);       // v_rcp_f32, ~1 ulp

    // edge_length: contiguous dword nt store
    if (valid) __builtin_nontemporal_store(r, &out[e]);

    // poly_cutoff p=6: 1 - 28 x^6 + 48 x^7 - 21 x^8, zero at x>=1
    float xr = r * 0.2f;                           // r / RC, RC=5
    float x3 = xr * xr * xr;
    float x6 = x3 * x3;
    float env = 1.0f - 28.0f * x6 + 48.0f * x6 * xr - 21.0f * x6 * xr * xr;
    env = (xr < 1.0f) ? env : 0.0f;

    float pref = 0.632455532034f * rinv * env;     // sqrt(2/5)

    // emb: 8 floats in output order, two swizzled b128 writes
    {
        f32x4 lo, hi;
        lo.x = pref * __sinf(coeffs[0] * xr);
        lo.y = pref * __sinf(coeffs[1] * xr);
        lo.z = pref * __sinf(coeffs[2] * xr);
        lo.w = pref * __sinf(coeffs[3] * xr);
        hi.x = pref * __sinf(coeffs[4] * xr);
        hi.y = pref * __sinf(coeffs[5] * xr);
        hi.z = pref * __sinf(coeffs[6] * xr);
        hi.w = pref * __sinf(coeffs[7] * xr);
        int s0 = 2 * lane;
        int s1 = 2 * lane + 1;
        ((f32x4*)s_emb[wid])[s0 ^ ((s0 >> 3) & 7)] = lo;
        ((f32x4*)s_emb[wid])[s1 ^ ((s1 >> 3) & 7)] = hi;
    }

    float ux = px * rinv, uy = py * rinv, uz = pz * rinv;
    const float s3 = 1.73205080757f, s15 = 3.87298334621f, s5 = 2.2360679775f;
    float sh1 = s3 * ux, sh2 = s3 * uy, sh3 = s3 * uz;
    if (isrev) { sh1 = -sh1; sh2 = -sh2; sh3 = -sh3; }   // SH parity on l=1
    s_attr[wid][9 * lane + 0] = 1.0f;
    s_attr[wid][9 * lane + 1] = sh1;
    s_attr[wid][9 * lane + 2] = sh2;
    s_attr[wid][9 * lane + 3] = sh3;
    s_attr[wid][9 * lane + 4] = s15 * ux * uy;
    s_attr[wid][9 * lane + 5] = s15 * uy * uz;
    s_attr[wid][9 * lane + 6] = 0.5f * s5 * (3.0f * uz * uz - 1.0f);
    s_attr[wid][9 * lane + 7] = s15 * ux * uz;
    s_attr[wid][9 * lane + 8] = 0.5f * s15 * (ux * ux - uy * uy);

    // --- per-wave coalesced nt stores
    f32x4* o4 = (f32x4*)out;

    // edge_embedding region: floats [E, 9E); wave chunk = 128 f4
    {
        int embB4   = (E >> 2) + (we0 << 1);
        int embEnd4 = (9 * E) >> 2;
#pragma unroll
        for (int kk = 0; kk < 2; kk++) {
            int k  = lane + (kk << 6);
            int g4 = embB4 + k;
            if (g4 < embEnd4) {
                f32x4 v = ((f32x4*)s_emb[wid])[k ^ ((k >> 3) & 7)];
                __builtin_nontemporal_store(v, &o4[g4]);
            }
        }
    }

    // edge_attr region: floats [9E, 18E); wave chunk = 144 f4
    {
        int attrB4   = ((9 * E) >> 2) + ((9 * we0) >> 2);   // 9*we0 div by 4
        int attrEnd4 = (18 * E) >> 2;                       // 13.5M < 2^31
#pragma unroll
        for (int kk = 0; kk < 3; kk++) {
            int k = lane + (kk << 6);
            if (k < 144) {
                int g4 = attrB4 + k;
                if (g4 < attrEnd4) {
                    f32x4 v = ((f32x4*)s_attr[wid])[k];
                    __builtin_nontemporal_store(v, &o4[g4]);
                }
            }
        }
    }
}

extern "C" void kernel_launch(void* const* d_in, const int* in_sizes, int n_in,
                              void* d_out, int out_size, void* d_ws, size_t ws_size,
                              hipStream_t stream) {
    const float* edge_vec = (const float*)d_in[0];
    const float* coeffs   = (const float*)d_in[1];
    const unsigned char* rev = (const unsigned char*)d_in[3];

    int E = in_sizes[2];          // 2P edges
    float* out = (float*)d_out;

    int eblocks = (E + TPB - 1) / TPB;
    edge_kernel<<<eblocks, TPB, 0, stream>>>(edge_vec, rev, coeffs, out, E);
}